// Round 1
// baseline (51.968 us; speedup 1.0000x reference)
//
#include <hip/hip_runtime.h>
#include <hip/hip_bf16.h>

// Problem: B=16384, I=512, H=512.
// Output = modrelu(complex(inputs@w_ih.T [:, :512], [:, 512:]), b_h)
// The FFT/reflect/perm state path in the reference is DEAD CODE (preact unused).

typedef __attribute__((ext_vector_type(8))) short bf16x8;
typedef __attribute__((ext_vector_type(4))) float f32x4;

#define BM 128
#define BK 64
#define KDIM 512
#define NDIM 1024

__device__ __forceinline__ unsigned short f2bf(float f) {
    unsigned u = __builtin_bit_cast(unsigned, f);
    u += 0x7fffu + ((u >> 16) & 1u);   // round-to-nearest-even
    return (unsigned short)(u >> 16);
}

__global__ void cvt_f32_bf16(const float* __restrict__ src,
                             unsigned short* __restrict__ dst, int n4) {
    int i = blockIdx.x * blockDim.x + threadIdx.x;
    int stride = gridDim.x * blockDim.x;
    for (; i < n4; i += stride) {
        float4 v = reinterpret_cast<const float4*>(src)[i];
        ushort4 o;
        o.x = f2bf(v.x); o.y = f2bf(v.y); o.z = f2bf(v.z); o.w = f2bf(v.w);
        reinterpret_cast<ushort4*>(dst)[i] = o;
    }
}

__device__ __forceinline__ void gload_lds16(const void* g, void* l) {
    __builtin_amdgcn_global_load_lds(
        (const __attribute__((address_space(1))) unsigned int*)g,
        (__attribute__((address_space(3))) unsigned int*)l, 16, 0, 0);
}

// C[m, n]       = re * scale,  C[m, 512+n] = im * scale
// re = sum_k A[m,k] W[n,k], im = sum_k A[m,k] W[512+n,k]
// Block: 128 M-rows x (64 re-cols + 64 im-cols). 4 waves, wave w owns rows w*32..w*32+31.
__global__ __launch_bounds__(256) void gemm_modrelu(
    const unsigned short* __restrict__ A,   // 16384 x 512 bf16
    const unsigned short* __restrict__ W,   // 1024 x 512 bf16
    const float* __restrict__ bh,           // 512
    float* __restrict__ out)                // 16384 x 1024 f32
{
    __shared__ unsigned short At[BM * BK];  // [row][slot^ (row&7)] 16B slots
    __shared__ unsigned short Bt[BM * BK];

    const int tid = threadIdx.x;
    const int w   = tid >> 6;
    const int l   = tid & 63;
    const int bx  = blockIdx.x;
    const int nb  = bx & 7;        // 8 n-blocks of 64 cols
    const int mb  = bx >> 3;       // 128 m-blocks of 128 rows

    const int l15 = l & 15;
    const int l4  = l >> 4;

    // staging constants: each issue stages 32 rows (8 per wave), lane l writes
    // physical 16B slot (l&7) of row (l>>3); source segment pre-swizzled.
    const int srow = w * 8 + (l >> 3);               // row within issue group (mod 32)
    const int sseg = (l & 7) ^ ((l >> 3) & 7);       // swizzled global segment
    const size_t a_rowbase = (size_t)mb * BM;

    f32x4 acc[2][8];
#pragma unroll
    for (int i = 0; i < 2; ++i)
#pragma unroll
        for (int j = 0; j < 8; ++j) acc[i][j] = f32x4{0.f, 0.f, 0.f, 0.f};

    for (int kt = 0; kt < KDIM / BK; ++kt) {
        const int k0 = kt * BK;
        // ---- stage A tile (128 x 64 bf16) ----
#pragma unroll
        for (int is = 0; is < 4; ++is) {
            int row = is * 32 + srow;
            const unsigned short* g = A + (a_rowbase + row) * KDIM + k0 + sseg * 8;
            unsigned short* lb = At + (is * 32 + w * 8) * BK;   // wave-uniform base
            gload_lds16(g, lb);
        }
        // ---- stage B tile: rows 0..63 = W[nb*64 + r], rows 64..127 = W[512 + nb*64 + r] ----
#pragma unroll
        for (int is = 0; is < 4; ++is) {
            int brow = is * 32 + srow;
            int wrow = nb * 64 + (brow & 63) + ((brow >> 6) << 9);
            const unsigned short* g = W + (size_t)wrow * KDIM + k0 + sseg * 8;
            unsigned short* lb = Bt + (is * 32 + w * 8) * BK;
            gload_lds16(g, lb);
        }
        __syncthreads();   // compiler drains vmcnt before barrier

        // ---- compute: 2 k-substeps of K=32, 2x8 fragments ----
#pragma unroll
        for (int ks = 0; ks < 2; ++ks) {
            bf16x8 af[2], bfr[8];
#pragma unroll
            for (int im = 0; im < 2; ++im) {
                int row  = w * 32 + im * 16 + l15;
                int slot = (ks * 4 + l4) ^ (row & 7);
                af[im] = *(const bf16x8*)(At + row * BK + slot * 8);
            }
#pragma unroll
            for (int jn = 0; jn < 8; ++jn) {
                int row  = jn * 16 + l15;
                int slot = (ks * 4 + l4) ^ (row & 7);
                bfr[jn] = *(const bf16x8*)(Bt + row * BK + slot * 8);
            }
#pragma unroll
            for (int im = 0; im < 2; ++im)
#pragma unroll
                for (int jn = 0; jn < 8; ++jn)
                    acc[im][jn] = __builtin_amdgcn_mfma_f32_16x16x32_bf16(
                        af[im], bfr[jn], acc[im][jn], 0, 0, 0);
        }
        __syncthreads();
    }

    // ---- fused modReLU epilogue ----
    // C/D layout (m89): col = lane&15, row = (lane>>4)*4 + j
#pragma unroll
    for (int jn = 0; jn < 4; ++jn) {
        int n = nb * 64 + jn * 16 + l15;
        float b = bh[n];
#pragma unroll
        for (int im = 0; im < 2; ++im) {
#pragma unroll
            for (int j = 0; j < 4; ++j) {
                int m = mb * BM + w * 32 + im * 16 + l4 * 4 + j;
                float re  = acc[im][jn][j];
                float imv = acc[im][jn + 4][j];
                float norm  = sqrtf(re * re + imv * imv);
                float scale = fmaxf(norm + b, 0.f) / (norm + 1e-6f);
                out[(size_t)m * NDIM + n]       = re  * scale;
                out[(size_t)m * NDIM + 512 + n] = imv * scale;
            }
        }
    }
}

extern "C" void kernel_launch(void* const* d_in, const int* in_sizes, int n_in,
                              void* d_out, int out_size, void* d_ws, size_t ws_size,
                              hipStream_t stream) {
    const float* inputs = (const float*)d_in[0];   // (16384, 512)
    const float* w_ih   = (const float*)d_in[2];   // (1024, 512)
    const float* b_h    = (const float*)d_in[3];   // (512,)
    float* out = (float*)d_out;                    // (16384, 1024)

    unsigned short* Abf = (unsigned short*)d_ws;                          // 16 MiB
    unsigned short* Wbf = (unsigned short*)((char*)d_ws + (size_t)16384 * 512 * 2);

    // convert inputs and weights to bf16
    cvt_f32_bf16<<<2048, 256, 0, stream>>>(inputs, Abf, (16384 * 512) / 4);
    cvt_f32_bf16<<<512,  256, 0, stream>>>(w_ih,   Wbf, (1024 * 512) / 4);

    // fused GEMM + modReLU: grid = (16384/128) m-blocks * 8 n-blocks
    gemm_modrelu<<<128 * 8, 256, 0, stream>>>(Abf, Wbf, b_h, out);
}